// Round 20
// baseline (364.940 us; speedup 1.0000x reference)
//
#include <hip/hip_runtime.h>

typedef __attribute__((ext_vector_type(8))) short short8;
typedef __attribute__((ext_vector_type(4))) short short4_t;
typedef __attribute__((ext_vector_type(4))) float floatx4;
typedef __attribute__((ext_vector_type(16))) float floatx16;

#define NTOK 8192
#define S_ 1024
#define DM 1024

__device__ __forceinline__ unsigned short f2b(float f) {
    union { float f; unsigned u; } v; v.f = f;
    unsigned r = v.u + 0x7FFF + ((v.u >> 16) & 1);
    return (unsigned short)(r >> 16);
}

__device__ __forceinline__ float b2f(unsigned short u) {
    union { unsigned u; float f; } v; v.u = ((unsigned)u) << 16;
    return v.f;
}

__device__ __forceinline__ void gl_lds16(const void* g, void* l) {
    __builtin_amdgcn_global_load_lds((const __attribute__((address_space(1))) void*)g,
                                     (__attribute__((address_space(3))) void*)l, 16, 0, 0);
}

// ---------------- fused preprocessing + LN1, ONE launch ----------------
__global__ __launch_bounds__(256) void prep_kernel(const float* __restrict__ wq,
                                                   const float* __restrict__ wk,
                                                   const float* __restrict__ wv,
                                                   const float* __restrict__ wo,
                                                   const float* __restrict__ w1,
                                                   const float* __restrict__ w2,
                                                   const float* __restrict__ bq,
                                                   const float* __restrict__ bk,
                                                   const float* __restrict__ bv,
                                                   const int* __restrict__ mask,
                                                   const float* __restrict__ x,
                                                   const float* __restrict__ g1,
                                                   const float* __restrict__ be1,
                                                   unsigned short* __restrict__ wqkv_bf,
                                                   unsigned short* __restrict__ wo_bf,
                                                   unsigned short* __restrict__ w1_bf,
                                                   unsigned short* __restrict__ w2_bf,
                                                   float* __restrict__ bqkv,
                                                   float* __restrict__ mbias,
                                                   int* __restrict__ mflags,
                                                   unsigned short* __restrict__ h_bf) {
    const int bid = blockIdx.x;
    const int t = threadIdx.x;
    if (bid < 12288) {
        const int q = bid * 256 + t;
        const float* src;
        unsigned short* dst;
        int lq;
        if (q < 786432) {
            src = (q < 262144) ? wq : (q < 524288 ? wk : wv);
            lq = q & 262143;
            dst = wqkv_bf + (size_t)(q >> 18) * 1048576;
        } else if (q < 1048576) {
            src = wo; lq = q - 786432; dst = wo_bf;
        } else if (q < 2097152) {
            src = w1; lq = q - 1048576; dst = w1_bf;
        } else {
            src = w2; lq = q - 2097152; dst = w2_bf;
        }
        const float4 v = *reinterpret_cast<const float4*>(src + (size_t)lq * 4);
        short4_t o;
        o.x = (short)f2b(v.x); o.y = (short)f2b(v.y);
        o.z = (short)f2b(v.z); o.w = (short)f2b(v.w);
        *reinterpret_cast<short4_t*>(dst + (size_t)lq * 4) = o;
        return;
    }
    if (bid == 12288) {
#pragma unroll
        for (int it = 0; it < 3; ++it) {
            const int q = t + it * 256;
            const float* src = (q < 256) ? bq : (q < 512 ? bk : bv);
            const int lq = q & 255;
            *reinterpret_cast<float4*>(bqkv + q * 4) =
                *reinterpret_cast<const float4*>(src + lq * 4);
        }
        return;
    }
    if (bid == 12289) {
#pragma unroll
        for (int it = 0; it < 8; ++it) {
            const int q = t + it * 256;
            const int4 m = *reinterpret_cast<const int4*>(mask + q * 4);
            float4 o;
            o.x = (m.x == 0) ? -1e9f : 0.f;
            o.y = (m.y == 0) ? -1e9f : 0.f;
            o.z = (m.z == 0) ? -1e9f : 0.f;
            o.w = (m.w == 0) ? -1e9f : 0.f;
            *reinterpret_cast<float4*>(mbias + q * 4) = o;
        }
        if (t < 128) {
            int f = 0;
            const int* mp = mask + t * 64;
#pragma unroll
            for (int k = 0; k < 64; ++k) f |= (mp[k] == 0) ? 1 : 0;
            mflags[t] = f;
        }
        return;
    }
    const int row = bid - 12290;
    const float4 xv = *reinterpret_cast<const float4*>(x + (size_t)row * DM + t * 4);
    float s = xv.x + xv.y + xv.z + xv.w;
#pragma unroll
    for (int off = 32; off > 0; off >>= 1) s += __shfl_down(s, off);
    __shared__ float red[8];
    const int wid = t >> 6, lane = t & 63;
    if (lane == 0) red[wid] = s;
    __syncthreads();
    const float mean = (red[0] + red[1] + red[2] + red[3]) * (1.f / 1024.f);
    const float dx = xv.x - mean, dy = xv.y - mean, dz = xv.z - mean, dw = xv.w - mean;
    float ss = dx * dx + dy * dy + dz * dz + dw * dw;
#pragma unroll
    for (int off = 32; off > 0; off >>= 1) ss += __shfl_down(ss, off);
    if (lane == 0) red[4 + wid] = ss;
    __syncthreads();
    const float var = (red[4] + red[5] + red[6] + red[7]) * (1.f / 1023.f);
    const float inv = 1.f / (sqrtf(var) + 1e-6f);
    const float4 gv = *reinterpret_cast<const float4*>(g1 + t * 4);
    const float4 bev = *reinterpret_cast<const float4*>(be1 + t * 4);
    short4_t o;
    o.x = (short)f2b(gv.x * dx * inv + bev.x);
    o.y = (short)f2b(gv.y * dy * inv + bev.y);
    o.z = (short)f2b(gv.z * dz * inv + bev.z);
    o.w = (short)f2b(gv.w * dw * inv + bev.w);
    *reinterpret_cast<short4_t*>(h_bf + (size_t)row * DM + t * 4) = o;
}

// ---------------- LayerNorm over bf16 input (LN2), out bf16 ----------------
__global__ __launch_bounds__(256) void ln_bf16(const unsigned short* __restrict__ xb,
                                               const float* __restrict__ g,
                                               const float* __restrict__ be,
                                               unsigned short* __restrict__ out) {
    const int row = blockIdx.x;
    const int t = threadIdx.x;
    const short4_t xv4 = *reinterpret_cast<const short4_t*>(xb + (size_t)row * DM + t * 4);
    float xv[4];
#pragma unroll
    for (int j = 0; j < 4; ++j) xv[j] = b2f((unsigned short)xv4[j]);
    float s = xv[0] + xv[1] + xv[2] + xv[3];
#pragma unroll
    for (int off = 32; off > 0; off >>= 1) s += __shfl_down(s, off);
    __shared__ float red[8];
    const int wid = t >> 6, lane = t & 63;
    if (lane == 0) red[wid] = s;
    __syncthreads();
    const float mean = (red[0] + red[1] + red[2] + red[3]) * (1.f / 1024.f);
    float d[4];
#pragma unroll
    for (int j = 0; j < 4; ++j) d[j] = xv[j] - mean;
    float ss = d[0] * d[0] + d[1] * d[1] + d[2] * d[2] + d[3] * d[3];
#pragma unroll
    for (int off = 32; off > 0; off >>= 1) ss += __shfl_down(ss, off);
    if (lane == 0) red[4 + wid] = ss;
    __syncthreads();
    const float var = (red[4] + red[5] + red[6] + red[7]) * (1.f / 1023.f);
    const float inv = 1.f / (sqrtf(var) + 1e-6f);
    const float4 gv = *reinterpret_cast<const float4*>(g + t * 4);
    const float4 bev = *reinterpret_cast<const float4*>(be + t * 4);
    short4_t o;
    o.x = (short)f2b(gv.x * d[0] * inv + bev.x);
    o.y = (short)f2b(gv.y * d[1] * inv + bev.y);
    o.z = (short)f2b(gv.z * d[2] * inv + bev.z);
    o.w = (short)f2b(gv.w * d[3] * inv + bev.w);
    *reinterpret_cast<short4_t*>(out + (size_t)row * DM + t * 4) = o;
}

// ---------------- 128x128 NT GEMM, bf16 in, fp32 acc, 32x32x16 MFMA ----------------
// EPI: 2 = bf16 out (+bias + fp32 residual), 4 = QKV scatter, 5 = fp32 out (+bias + bf16 res)
template <int EPI>
__global__ __launch_bounds__(256, 2) void gemm_bt(const unsigned short* __restrict__ A,
                                                  const unsigned short* __restrict__ Bm,
                                                  const float* __restrict__ bias,
                                                  const void* __restrict__ res,
                                                  void* __restrict__ outp,
                                                  int M, int N, int K, int tilesX) {
    __shared__ __align__(16) unsigned short lds[2][2][8192];
    const int t = threadIdx.x;
    const int lane = t & 63, wid = t >> 6;
    const int wr = wid >> 1, wc = wid & 1;

    const int bid = blockIdx.x;
    const int xcd = bid & 7;
    const int lid = bid >> 3;
    const int sid = lid >> 5;
    const int off = lid & 31;
    const int gsid = sid * 8 + xcd;
    const int supercols = tilesX >> 2;
    const int srow = gsid / supercols;
    const int scol = gsid - srow * supercols;
    const int rowBase = (srow * 8 + (off >> 2)) * 128;
    const int colBase = (scol * 4 + (off & 3)) * 128;

    const int NT = K >> 6;
    const int lr31 = lane & 31;
    const int kh = lane >> 5;

    const unsigned short* Ag[4];
    const unsigned short* Bg[4];
#pragma unroll
    for (int j = 0; j < 4; ++j) {
        const int L = j * 256 + t;
        const int r = L >> 3;
        const int c = ((L & 7) ^ (r & 7)) * 8;
        Ag[j] = A + (size_t)(rowBase + r) * K + c;
        Bg[j] = Bm + (size_t)(colBase + r) * K + c;
    }

    floatx16 acc[2][2] = {};

#pragma unroll
    for (int j = 0; j < 4; ++j) gl_lds16(Ag[j], &lds[0][0][j * 2048 + wid * 512]);
#pragma unroll
    for (int j = 0; j < 4; ++j) gl_lds16(Bg[j], &lds[0][1][j * 2048 + wid * 512]);
#pragma unroll
    for (int j = 0; j < 4; ++j) { Ag[j] += 64; Bg[j] += 64; }

    int cur = 0;
    for (int tt = 0; tt < NT; ++tt) {
        if (tt + 1 < NT) {
#pragma unroll
            for (int j = 0; j < 4; ++j)
                gl_lds16(Ag[j], &lds[cur ^ 1][0][j * 2048 + wid * 512]);
#pragma unroll
            for (int j = 0; j < 4; ++j)
                gl_lds16(Bg[j], &lds[cur ^ 1][1][j * 2048 + wid * 512]);
#pragma unroll
            for (int j = 0; j < 4; ++j) { Ag[j] += 64; Bg[j] += 64; }
            asm volatile("s_waitcnt vmcnt(8)" ::: "memory");
        } else {
            asm volatile("s_waitcnt vmcnt(0)" ::: "memory");
        }
        __builtin_amdgcn_s_barrier();
        __builtin_amdgcn_sched_barrier(0);
        const unsigned short* Ab = &lds[cur][0][0];
        const unsigned short* Bb = &lds[cur][1][0];
#pragma unroll
        for (int ks = 0; ks < 4; ++ks) {
            short8 af[2], bfr[2];
#pragma unroll
            for (int mf = 0; mf < 2; ++mf) {
                const int r = wr * 64 + mf * 32 + lr31;
                const int cp = (ks * 2 + kh) ^ (r & 7);
                af[mf] = *reinterpret_cast<const short8*>(&Ab[r * 64 + cp * 8]);
            }
#pragma unroll
            for (int nf = 0; nf < 2; ++nf) {
                const int r = wc * 64 + nf * 32 + lr31;
                const int cp = (ks * 2 + kh) ^ (r & 7);
                bfr[nf] = *reinterpret_cast<const short8*>(&Bb[r * 64 + cp * 8]);
            }
            __builtin_amdgcn_s_setprio(1);
#pragma unroll
            for (int mf = 0; mf < 2; ++mf)
#pragma unroll
                for (int nf = 0; nf < 2; ++nf)
                    acc[mf][nf] = __builtin_amdgcn_mfma_f32_32x32x16_bf16(af[mf], bfr[nf], acc[mf][nf], 0, 0, 0);
            __builtin_amdgcn_s_setprio(0);
        }
        __builtin_amdgcn_sched_barrier(0);
        __builtin_amdgcn_s_barrier();
        cur ^= 1;
    }

    const int rbw = rowBase + wr * 64;
    const int cbw = colBase + wc * 64;
    const int lc31 = lane & 31;
    if (EPI == 4) {
        unsigned short* qh = (unsigned short*)outp;
        const float SC2 = 0.18033688f;
#pragma unroll
        for (int nf = 0; nf < 2; ++nf) {
            const int c = cbw + nf * 32 + lc31;
            const float bn = bias[c];
            const int sect = c >> 10;
            const int hh = (c >> 6) & 15;
            const int dd = c & 63;
            const float scl = (sect == 0) ? SC2 : 1.f;
#pragma unroll
            for (int mf = 0; mf < 2; ++mf) {
#pragma unroll
                for (int rg = 0; rg < 4; ++rg) {
                    const int r0 = rbw + mf * 32 + rg * 8 + 4 * kh;
                    const int bb = r0 >> 10, ss = r0 & 1023;
                    if (sect == 2) {
                        short4_t pk;
#pragma unroll
                        for (int j = 0; j < 4; ++j) pk[j] = (short)f2b(acc[mf][nf][rg * 4 + j] + bn);
                        *reinterpret_cast<short4_t*>(
                            &qh[16777216 + ((size_t)((bb * 16 + hh) * 64 + dd)) * 1024 + ss]) = pk;
                    } else {
                        unsigned short* base = qh + sect * 8388608;
#pragma unroll
                        for (int j = 0; j < 4; ++j)
                            base[((size_t)((bb * 16 + hh) * 1024 + ss + j)) * 64 + dd] =
                                f2b((acc[mf][nf][rg * 4 + j] + bn) * scl);
                    }
                }
            }
        }
        return;
    }
#pragma unroll
    for (int nf = 0; nf < 2; ++nf) {
        const int c = cbw + nf * 32 + lc31;
        const float bn = bias[c];
#pragma unroll
        for (int mf = 0; mf < 2; ++mf) {
#pragma unroll
            for (int rg = 0; rg < 4; ++rg) {
#pragma unroll
                for (int j = 0; j < 4; ++j) {
                    const int r = rbw + mf * 32 + rg * 8 + 4 * kh + j;
                    if (EPI == 2) {
                        const float v = acc[mf][nf][rg * 4 + j] + bn +
                                        ((const float*)res)[(size_t)r * N + c];
                        ((unsigned short*)outp)[(size_t)r * N + c] = f2b(v);
                    } else {
                        const float v = acc[mf][nf][rg * 4 + j] + bn +
                                        b2f(((const unsigned short*)res)[(size_t)r * N + c]);
                        ((float*)outp)[(size_t)r * N + c] = v;
                    }
                }
            }
        }
    }
}

// ---------------- Phase-pipelined 256x256 NT GEMM (FFN1): bf16 relu(+bias) out ----------------
__global__ __launch_bounds__(512, 2) void gemm256p(const unsigned short* __restrict__ A,
                                                   const unsigned short* __restrict__ Bm,
                                                   const float* __restrict__ bias,
                                                   unsigned short* __restrict__ outp,
                                                   int M, int N, int K, int tilesX) {
    __shared__ __align__(16) unsigned short Abuf[2][16384];
    __shared__ __align__(16) unsigned short Bbuf[2][16384];
    const int t = threadIdx.x;
    const int lane = t & 63, wid = t >> 6;
    const int wr = wid >> 2, wc = wid & 3;

    const int bid = blockIdx.x;
    const int xcd = bid & 7;
    const int lid = bid >> 3;
    const int sid = lid >> 5;
    const int off = lid & 31;
    const int gsid = sid * 8 + xcd;
    const int supercols = tilesX >> 2;
    const int srow = gsid / supercols;
    const int scol = gsid - srow * supercols;
    const int rowBase = (srow * 8 + (off >> 2)) * 256;
    const int colBase = (scol * 4 + (off & 3)) * 256;

    const int NT = K >> 6;
    const int lr31 = lane & 31;
    const int kh = lane >> 5;
    const int x7 = lane & 7;

    const int rho_s = t >> 3;
    const int csrc = ((t & 7) ^ (rho_s & 7)) * 8;
    const int ldst = t * 8;
    const unsigned short* Bs_[2][2];
    const unsigned short* As_[2][2];
#pragma unroll
    for (int h = 0; h < 2; ++h)
#pragma unroll
        for (int j = 0; j < 2; ++j) {
            const int rr = rho_s + j * 64;
            Bs_[h][j] = Bm + (size_t)(colBase + h * 128 + rr) * K + csrc;
            As_[h][j] = A + (size_t)(rowBase + ((rr >> 6) * 128 + h * 64 + (rr & 63))) * K + csrc;
        }

#define STG_BH(h_, b_, kk_)                                                   \
    do {                                                                      \
        gl_lds16(Bs_[h_][0] + (kk_), &Bbuf[b_][(h_)*8192 + ldst]);            \
        gl_lds16(Bs_[h_][1] + (kk_), &Bbuf[b_][(h_)*8192 + 4096 + ldst]);     \
    } while (0)
#define STG_AH(h_, b_, kk_)                                                   \
    do {                                                                      \
        gl_lds16(As_[h_][0] + (kk_), &Abuf[b_][(h_)*8192 + ldst]);            \
        gl_lds16(As_[h_][1] + (kk_), &Abuf[b_][(h_)*8192 + 4096 + ldst]);     \
    } while (0)

    floatx16 acc[4][2] = {};

    STG_BH(0, 0, 0); STG_BH(1, 0, 0); STG_AH(0, 0, 0); STG_AH(1, 0, 0);
    asm volatile("s_waitcnt vmcnt(0)" ::: "memory");
    __builtin_amdgcn_s_barrier();

    for (int kt = 0; kt < NT; ++kt) {
        const int cur = kt & 1, nxt = cur ^ 1;
        const bool pf = (kt + 1 < NT);
        const int kkn = (pf ? kt + 1 : kt) << 6;
        short8 bfr[2][4];
#pragma unroll
        for (int q = 0; q < 4; ++q) {
            short8 af[4];
            {
                const int rho = wr * 64 + (q & 1) * 32 + lr31;
                const unsigned short* Ab = &Abuf[cur][(q >> 1) * 8192];
#pragma unroll
                for (int s = 0; s < 4; ++s)
                    af[s] = *reinterpret_cast<const short8*>(
                        &Ab[rho * 64 + ((2 * s + kh) ^ x7) * 8]);
            }
            if (q == 0) {
#pragma unroll
                for (int nf = 0; nf < 2; ++nf) {
                    const int gcol = wc * 64 + nf * 32 + lr31;
                    const unsigned short* Bb = &Bbuf[cur][(gcol >> 7) * 8192];
                    const int rho = gcol & 127;
#pragma unroll
                    for (int s = 0; s < 4; ++s)
                        bfr[nf][s] = *reinterpret_cast<const short8*>(
                            &Bb[rho * 64 + ((2 * s + kh) ^ x7) * 8]);
                }
            }
            if (pf) {
                if (q == 0) STG_BH(0, nxt, kkn);
                if (q == 1) STG_BH(1, nxt, kkn);
                if (q == 2) STG_AH(0, nxt, kkn);
                if (q == 3) STG_AH(1, nxt, kkn);
            }
            __builtin_amdgcn_s_barrier();
            asm volatile("s_waitcnt lgkmcnt(0)" ::: "memory");
            __builtin_amdgcn_sched_barrier(0);
            __builtin_amdgcn_s_setprio(1);
#pragma unroll
            for (int s = 0; s < 4; ++s)
#pragma unroll
                for (int nf = 0; nf < 2; ++nf)
                    acc[q][nf] = __builtin_amdgcn_mfma_f32_32x32x16_bf16(af[s], bfr[nf][s], acc[q][nf], 0, 0, 0);
            __builtin_amdgcn_s_setprio(0);
            __builtin_amdgcn_sched_barrier(0);
            if (q == 1) {
                if (pf) asm volatile("s_waitcnt vmcnt(4)" ::: "memory");
                else    asm volatile("s_waitcnt vmcnt(0)" ::: "memory");
            }
            if (q == 3 && pf) asm volatile("s_waitcnt vmcnt(2)" ::: "memory");
            __builtin_amdgcn_s_barrier();
        }
    }
#undef STG_AH
#undef STG_BH

    const int rbw = rowBase + wr * 128;
    const int cbw = colBase + wc * 64;
    const int lc31 = lane & 31;
#pragma unroll
    for (int nf = 0; nf < 2; ++nf) {
        const int c = cbw + nf * 32 + lc31;
        const float bn = bias[c];
#pragma unroll
        for (int q = 0; q < 4; ++q) {
#pragma unroll
            for (int rg = 0; rg < 4; ++rg) {
                const int r0 = rbw + q * 32 + rg * 8 + 4 * kh;
#pragma unroll
                for (int j = 0; j < 4; ++j) {
                    const float v = fmaxf(acc[q][nf][rg * 4 + j] + bn, 0.f);
                    outp[(size_t)(r0 + j) * N + c] = f2b(v);
                }
            }
        }
    }
}

// ---------------- MFMA flash attention: ring-4 K/V slots, single barrier per chunk ----------------
// Stage-ahead 2 into a 4-slot ring: stage(kc+2) targets slot (kc+2)&3 whose last reader
// (iter kc-2) is separated by barriers kc-1 and kc -> trailing barrier unnecessary.
// vmcnt before barrier: slot (kc)&3 was staged at iter kc-2; loads issued after it =
// iters kc-1 and kc = 8 (kc<14), 4 (kc==14), 0 (kc==15).
__global__ __launch_bounds__(256) void attn_mfma(const unsigned short* __restrict__ Qh,
                                                 const unsigned short* __restrict__ Kh,
                                                 const unsigned short* __restrict__ Vt,
                                                 const float* __restrict__ mbias,
                                                 const int* __restrict__ mflags,
                                                 unsigned short* __restrict__ out) {
    __shared__ __align__(16) unsigned short Kbuf[4][4096];
    __shared__ __align__(16) unsigned short Vbuf[4][4096];
    __shared__ __align__(16) unsigned short Pbuf[4][16][72];
    __shared__ __align__(16) float mk[1024];
    const int t = threadIdx.x;
    const int w = t >> 6, l = t & 63;
    const int g = l >> 4, q16 = l & 15;
    const int x7 = q16 & 7;
    const int bid = blockIdx.x;
    const int swz = (bid & 7) * 256 + (bid >> 3);
    const int bh = swz >> 4, qb = swz & 15;
    const int b = bh >> 4, h = bh & 15;

    const size_t qbase = ((size_t)bh * 1024 + qb * 64 + w * 16 + q16) * 64;
    const short8 qf0 = *reinterpret_cast<const short8*>(Qh + qbase + g * 8);
    const short8 qf1 = *reinterpret_cast<const short8*>(Qh + qbase + 32 + g * 8);

    const int r0 = t >> 3;
    const int c0 = ((t & 7) ^ (r0 & 7)) * 8;
    const unsigned short* Kg = Kh + (size_t)bh * 65536 + r0 * 64 + c0;
    const unsigned short* Vg = Vt + (size_t)bh * 65536 + r0 * 1024 + c0;

#define ATTN_STAGE(bi, kc_)                                                        \
    do {                                                                           \
        gl_lds16(Kg + (kc_) * 4096, &Kbuf[bi][w * 512]);                           \
        gl_lds16(Kg + (kc_) * 4096 + 2048, &Kbuf[bi][2048 + w * 512]);             \
        gl_lds16(Vg + (kc_) * 64, &Vbuf[bi][w * 512]);                             \
        gl_lds16(Vg + (kc_) * 64 + 32768, &Vbuf[bi][2048 + w * 512]);              \
    } while (0)

    // prologue: mask + chunks 0,1 (slots 0,1)
    gl_lds16(mbias + b * 1024 + t * 4, &mk[w * 256]);
    ATTN_STAGE(0, 0);
    ATTN_STAGE(1, 1);

    floatx4 oacc[4] = {};
    floatx4 loacc = {};
    short8 ones;
#pragma unroll
    for (int j = 0; j < 8; ++j) ones[j] = (short)0x3F80;  // bf16 1.0

    for (int kc = 0; kc < 16; ++kc) {
        if (kc + 2 < 16) {
            ATTN_STAGE((kc + 2) & 3, kc + 2);
            asm volatile("s_waitcnt vmcnt(8)" ::: "memory");
        } else if (kc + 1 < 16) {
            asm volatile("s_waitcnt vmcnt(4)" ::: "memory");
        } else {
            asm volatile("s_waitcnt vmcnt(0)" ::: "memory");
        }
        __builtin_amdgcn_s_barrier();
        __builtin_amdgcn_sched_barrier(0);
        const unsigned short* Kb = Kbuf[kc & 3];
        const unsigned short* Vb = Vbuf[kc & 3];

        floatx4 st[4] = {};
        __builtin_amdgcn_s_setprio(1);
#pragma unroll
        for (int t4 = 0; t4 < 4; ++t4) {
            const int row = t4 * 16 + q16;
            const short8 kf0 = *reinterpret_cast<const short8*>(&Kb[row * 64 + (g ^ x7) * 8]);
            const short8 kf1 = *reinterpret_cast<const short8*>(&Kb[row * 64 + ((4 + g) ^ x7) * 8]);
            st[t4] = __builtin_amdgcn_mfma_f32_16x16x32_bf16(kf0, qf0, st[t4], 0, 0, 0);
            st[t4] = __builtin_amdgcn_mfma_f32_16x16x32_bf16(kf1, qf1, st[t4], 0, 0, 0);
        }
        __builtin_amdgcn_s_setprio(0);

        if (mflags[b * 16 + kc]) {
#pragma unroll
            for (int t4 = 0; t4 < 4; ++t4) {
                const float4 mbv = *reinterpret_cast<const float4*>(&mk[kc * 64 + t4 * 16 + g * 4]);
#pragma unroll
                for (int r = 0; r < 4; ++r) st[t4][r] += ((const float*)&mbv)[r];
            }
        }
#pragma unroll
        for (int t4 = 0; t4 < 4; ++t4) {
            const float p0 = __builtin_exp2f(st[t4][0]);
            const float p1 = __builtin_exp2f(st[t4][1]);
            const float p2 = __builtin_exp2f(st[t4][2]);
            const float p3 = __builtin_exp2f(st[t4][3]);
            unsigned u0, u1;
            asm("v_cvt_pk_bf16_f32 %0, %1, %2" : "=v"(u0) : "v"(p0), "v"(p1));
            asm("v_cvt_pk_bf16_f32 %0, %1, %2" : "=v"(u1) : "v"(p2), "v"(p3));
            uint2 pr; pr.x = u0; pr.y = u1;
            *reinterpret_cast<uint2*>(&Pbuf[w][q16][t4 * 16 + g * 4]) = pr;
        }

        const short8 pf0 = *reinterpret_cast<const short8*>(&Pbuf[w][q16][g * 8]);
        const short8 pf1 = *reinterpret_cast<const short8*>(&Pbuf[w][q16][32 + g * 8]);
        __builtin_amdgcn_s_setprio(1);
        loacc = __builtin_amdgcn_mfma_f32_16x16x32_bf16(pf0, ones, loacc, 0, 0, 0);
        loacc = __builtin_amdgcn_mfma_f32_16x16x32_bf16(pf1, ones, loacc, 0, 0, 0);
#pragma unroll
        for (int n = 0; n < 4; ++n) {
            const int row = n * 16 + q16;
            const short8 vf0 = *reinterpret_cast<const short8*>(&Vb[row * 64 + (g ^ x7) * 8]);
            const short8 vf1 = *reinterpret_cast<const short8*>(&Vb[row * 64 + ((4 + g) ^ x7) * 8]);
            oacc[n] = __builtin_amdgcn_mfma_f32_16x16x32_bf16(pf0, vf0, oacc[n], 0, 0, 0);
            oacc[n] = __builtin_amdgcn_mfma_f32_16x16x32_bf16(pf1, vf1, oacc[n], 0, 0, 0);
        }
        __builtin_amdgcn_s_setprio(0);
        __builtin_amdgcn_sched_barrier(0);
    }
#undef ATTN_STAGE

    const size_t obase = ((size_t)b * S_ + qb * 64 + w * 16) * 1024 + h * 64;
#pragma unroll
    for (int r = 0; r < 4; ++r) {
        const float invr = 1.f / loacc[r];
        const size_t orow = obase + (size_t)(g * 4 + r) * 1024;
#pragma unroll
        for (int n = 0; n < 4; ++n)
            out[orow + n * 16 + q16] = f2b(oacc[n][r] * invr);
    }
}

extern "C" void kernel_launch(void* const* d_in, const int* in_sizes, int n_in,
                              void* d_out, int out_size, void* d_ws, size_t ws_size,
                              hipStream_t stream) {
    const float* x   = (const float*)d_in[0];
    const int*  mask = (const int*)d_in[1];
    const float* wq  = (const float*)d_in[2];
    const float* bq  = (const float*)d_in[3];
    const float* wk  = (const float*)d_in[4];
    const float* bk  = (const float*)d_in[5];
    const float* wv  = (const float*)d_in[6];
    const float* bv  = (const float*)d_in[7];
    const float* wo  = (const float*)d_in[8];
    const float* bo  = (const float*)d_in[9];
    const float* w1  = (const float*)d_in[10];
    const float* b1  = (const float*)d_in[11];
    const float* w2  = (const float*)d_in[12];
    const float* b2  = (const float*)d_in[13];
    const float* g1  = (const float*)d_in[14];
    const float* be1 = (const float*)d_in[15];
    const float* g2  = (const float*)d_in[16];
    const float* be2 = (const float*)d_in[17];

    char* ws = (char*)d_ws;
    unsigned short* wqkv_bf = (unsigned short*)(ws);                 // 6 MB
    unsigned short* wo_bf   = (unsigned short*)(ws + 6291456);       // 2 MB
    unsigned short* w1_bf   = (unsigned short*)(ws + 8388608);       // 8 MB
    unsigned short* w2_bf   = (unsigned short*)(ws + 16777216);      // 8 MB
    float*          bqkv    = (float*)(ws + 25165824);               // 12 KB
    float*          mbias   = (float*)(ws + 25178112);               // 32 KB
    int*            mflags  = (int*)(ws + 25210880);                 // 512 B
    unsigned short* h_bf    = (unsigned short*)(ws + 25214976);      // 16 MB
    unsigned short* x1b     = (unsigned short*)(ws + 41992192);      // 16 MB (bf16 x1)
    unsigned short* attn_bf = (unsigned short*)(ws + 75546624);      // 16 MB
    unsigned short* qkvh    = (unsigned short*)(ws + 92323840);      // 48 MB: Qh|Kh|Vt
    unsigned short* ff1_bf  = (unsigned short*)(ws + 92323840);      // 64 MB (overlays qkvh after attn)

    // fused preprocessing + LN1: ONE launch
    prep_kernel<<<20482, 256, 0, stream>>>(wq, wk, wv, wo, w1, w2, bq, bk, bv, mask,
                                           x, g1, be1,
                                           wqkv_bf, wo_bf, w1_bf, w2_bf, bqkv, mbias, mflags, h_bf);

    // QKV projection (128² tiles: 24 x 64), scatter to Qh/Kh/Vt, Q pre-scaled
    gemm_bt<4><<<24 * 64, 256, 0, stream>>>(h_bf, wqkv_bf, bqkv, nullptr, qkvh, NTOK, 3072, 1024, 24);
    // flash attention (ring-4 slots, single barrier per chunk)
    attn_mfma<<<2048, 256, 0, stream>>>(qkvh, qkvh + 8388608, qkvh + 16777216, mbias, mflags, attn_bf);
    // O-projection + residual -> bf16 x1b (128² tiles: 8 x 64)
    gemm_bt<2><<<8 * 64, 256, 0, stream>>>(attn_bf, wo_bf, bo, x, x1b, NTOK, 1024, 1024, 8);
    // LN2 (bf16 input)
    ln_bf16<<<NTOK, 256, 0, stream>>>(x1b, g2, be2, h_bf);
    // FFN1 + ReLU (phase-pipelined 256² tiles: 32 x 16 = 512 blocks)
    gemm256p<<<512, 512, 0, stream>>>(h_bf, w1_bf, b1, ff1_bf, NTOK, 4096, 1024, 16);
    // FFN2 + bf16 residual -> fp32 out (128² tiles: 8 x 64)
    gemm_bt<5><<<8 * 64, 256, 0, stream>>>(ff1_bf, w2_bf, b2, x1b, (float*)d_out, NTOK, 1024, 4096, 8);
}

// Round 21
// 356.711 us; speedup vs baseline: 1.0231x; 1.0231x over previous
//
#include <hip/hip_runtime.h>

typedef __attribute__((ext_vector_type(8))) short short8;
typedef __attribute__((ext_vector_type(4))) short short4_t;
typedef __attribute__((ext_vector_type(4))) float floatx4;
typedef __attribute__((ext_vector_type(16))) float floatx16;

#define NTOK 8192
#define S_ 1024
#define DM 1024

__device__ __forceinline__ unsigned short f2b(float f) {
    union { float f; unsigned u; } v; v.f = f;
    unsigned r = v.u + 0x7FFF + ((v.u >> 16) & 1);
    return (unsigned short)(r >> 16);
}

__device__ __forceinline__ float b2f(unsigned short u) {
    union { unsigned u; float f; } v; v.u = ((unsigned)u) << 16;
    return v.f;
}

__device__ __forceinline__ void gl_lds16(const void* g, void* l) {
    __builtin_amdgcn_global_load_lds((const __attribute__((address_space(1))) void*)g,
                                     (__attribute__((address_space(3))) void*)l, 16, 0, 0);
}

// ---------------- fused preprocessing + LN1, ONE launch ----------------
// blocks 0..12287: weight fp32->bf16 (1 quad/thread)
// block 12288: bqkv copy; block 12289: mbias + mflags; blocks 12290..20481: LN1 rows
__global__ __launch_bounds__(256) void prep_kernel(const float* __restrict__ wq,
                                                   const float* __restrict__ wk,
                                                   const float* __restrict__ wv,
                                                   const float* __restrict__ wo,
                                                   const float* __restrict__ w1,
                                                   const float* __restrict__ w2,
                                                   const float* __restrict__ bq,
                                                   const float* __restrict__ bk,
                                                   const float* __restrict__ bv,
                                                   const int* __restrict__ mask,
                                                   const float* __restrict__ x,
                                                   const float* __restrict__ g1,
                                                   const float* __restrict__ be1,
                                                   unsigned short* __restrict__ wqkv_bf,
                                                   unsigned short* __restrict__ wo_bf,
                                                   unsigned short* __restrict__ w1_bf,
                                                   unsigned short* __restrict__ w2_bf,
                                                   float* __restrict__ bqkv,
                                                   float* __restrict__ mbias,
                                                   int* __restrict__ mflags,
                                                   unsigned short* __restrict__ h_bf) {
    const int bid = blockIdx.x;
    const int t = threadIdx.x;
    if (bid < 12288) {
        const int q = bid * 256 + t;
        const float* src;
        unsigned short* dst;
        int lq;
        if (q < 786432) {            // wq|wk|wv -> wqkv_bf (contiguous layout)
            src = (q < 262144) ? wq : (q < 524288 ? wk : wv);
            lq = q & 262143;
            dst = wqkv_bf + (size_t)(q >> 18) * 1048576;
        } else if (q < 1048576) {
            src = wo; lq = q - 786432; dst = wo_bf;
        } else if (q < 2097152) {
            src = w1; lq = q - 1048576; dst = w1_bf;
        } else {
            src = w2; lq = q - 2097152; dst = w2_bf;
        }
        const float4 v = *reinterpret_cast<const float4*>(src + (size_t)lq * 4);
        short4_t o;
        o.x = (short)f2b(v.x); o.y = (short)f2b(v.y);
        o.z = (short)f2b(v.z); o.w = (short)f2b(v.w);
        *reinterpret_cast<short4_t*>(dst + (size_t)lq * 4) = o;
        return;
    }
    if (bid == 12288) {
#pragma unroll
        for (int it = 0; it < 3; ++it) {
            const int q = t + it * 256;
            const float* src = (q < 256) ? bq : (q < 512 ? bk : bv);
            const int lq = q & 255;
            *reinterpret_cast<float4*>(bqkv + q * 4) =
                *reinterpret_cast<const float4*>(src + lq * 4);
        }
        return;
    }
    if (bid == 12289) {
#pragma unroll
        for (int it = 0; it < 8; ++it) {
            const int q = t + it * 256;
            const int4 m = *reinterpret_cast<const int4*>(mask + q * 4);
            float4 o;
            o.x = (m.x == 0) ? -1e9f : 0.f;
            o.y = (m.y == 0) ? -1e9f : 0.f;
            o.z = (m.z == 0) ? -1e9f : 0.f;
            o.w = (m.w == 0) ? -1e9f : 0.f;
            *reinterpret_cast<float4*>(mbias + q * 4) = o;
        }
        if (t < 128) {
            int f = 0;
            const int* mp = mask + t * 64;
#pragma unroll
            for (int k = 0; k < 64; ++k) f |= (mp[k] == 0) ? 1 : 0;
            mflags[t] = f;
        }
        return;
    }
    // LN1 rows
    const int row = bid - 12290;
    const float4 xv = *reinterpret_cast<const float4*>(x + (size_t)row * DM + t * 4);
    float s = xv.x + xv.y + xv.z + xv.w;
#pragma unroll
    for (int off = 32; off > 0; off >>= 1) s += __shfl_down(s, off);
    __shared__ float red[8];
    const int wid = t >> 6, lane = t & 63;
    if (lane == 0) red[wid] = s;
    __syncthreads();
    const float mean = (red[0] + red[1] + red[2] + red[3]) * (1.f / 1024.f);
    const float dx = xv.x - mean, dy = xv.y - mean, dz = xv.z - mean, dw = xv.w - mean;
    float ss = dx * dx + dy * dy + dz * dz + dw * dw;
#pragma unroll
    for (int off = 32; off > 0; off >>= 1) ss += __shfl_down(ss, off);
    if (lane == 0) red[4 + wid] = ss;
    __syncthreads();
    const float var = (red[4] + red[5] + red[6] + red[7]) * (1.f / 1023.f);
    const float inv = 1.f / (sqrtf(var) + 1e-6f);
    const float4 gv = *reinterpret_cast<const float4*>(g1 + t * 4);
    const float4 bev = *reinterpret_cast<const float4*>(be1 + t * 4);
    short4_t o;
    o.x = (short)f2b(gv.x * dx * inv + bev.x);
    o.y = (short)f2b(gv.y * dy * inv + bev.y);
    o.z = (short)f2b(gv.z * dz * inv + bev.z);
    o.w = (short)f2b(gv.w * dw * inv + bev.w);
    *reinterpret_cast<short4_t*>(h_bf + (size_t)row * DM + t * 4) = o;
}

// ---------------- LayerNorm over bf16 input (LN2), out bf16 ----------------
__global__ __launch_bounds__(256) void ln_bf16(const unsigned short* __restrict__ xb,
                                               const float* __restrict__ g,
                                               const float* __restrict__ be,
                                               unsigned short* __restrict__ out) {
    const int row = blockIdx.x;
    const int t = threadIdx.x;
    const short4_t xv4 = *reinterpret_cast<const short4_t*>(xb + (size_t)row * DM + t * 4);
    float xv[4];
#pragma unroll
    for (int j = 0; j < 4; ++j) xv[j] = b2f((unsigned short)xv4[j]);
    float s = xv[0] + xv[1] + xv[2] + xv[3];
#pragma unroll
    for (int off = 32; off > 0; off >>= 1) s += __shfl_down(s, off);
    __shared__ float red[8];
    const int wid = t >> 6, lane = t & 63;
    if (lane == 0) red[wid] = s;
    __syncthreads();
    const float mean = (red[0] + red[1] + red[2] + red[3]) * (1.f / 1024.f);
    float d[4];
#pragma unroll
    for (int j = 0; j < 4; ++j) d[j] = xv[j] - mean;
    float ss = d[0] * d[0] + d[1] * d[1] + d[2] * d[2] + d[3] * d[3];
#pragma unroll
    for (int off = 32; off > 0; off >>= 1) ss += __shfl_down(ss, off);
    if (lane == 0) red[4 + wid] = ss;
    __syncthreads();
    const float var = (red[4] + red[5] + red[6] + red[7]) * (1.f / 1023.f);
    const float inv = 1.f / (sqrtf(var) + 1e-6f);
    const float4 gv = *reinterpret_cast<const float4*>(g + t * 4);
    const float4 bev = *reinterpret_cast<const float4*>(be + t * 4);
    short4_t o;
    o.x = (short)f2b(gv.x * d[0] * inv + bev.x);
    o.y = (short)f2b(gv.y * d[1] * inv + bev.y);
    o.z = (short)f2b(gv.z * d[2] * inv + bev.z);
    o.w = (short)f2b(gv.w * d[3] * inv + bev.w);
    *reinterpret_cast<short4_t*>(out + (size_t)row * DM + t * 4) = o;
}

// ---------------- 128x128 NT GEMM, bf16 in, fp32 acc, 32x32x16 MFMA ----------------
// EPI: 2 = bf16 out (+bias + fp32 residual)  [O-proj -> x1b]
//      4 = QKV scatter (Qh pre-scaled | Kh | Vt)
//      5 = fp32 out (+bias + bf16 residual)  [FFN2 -> d_out]
template <int EPI>
__global__ __launch_bounds__(256, 2) void gemm_bt(const unsigned short* __restrict__ A,
                                                  const unsigned short* __restrict__ Bm,
                                                  const float* __restrict__ bias,
                                                  const void* __restrict__ res,
                                                  void* __restrict__ outp,
                                                  int M, int N, int K, int tilesX) {
    __shared__ __align__(16) unsigned short lds[2][2][8192];
    const int t = threadIdx.x;
    const int lane = t & 63, wid = t >> 6;
    const int wr = wid >> 1, wc = wid & 1;

    const int bid = blockIdx.x;
    const int xcd = bid & 7;
    const int lid = bid >> 3;
    const int sid = lid >> 5;
    const int off = lid & 31;
    const int gsid = sid * 8 + xcd;
    const int supercols = tilesX >> 2;
    const int srow = gsid / supercols;
    const int scol = gsid - srow * supercols;
    const int rowBase = (srow * 8 + (off >> 2)) * 128;
    const int colBase = (scol * 4 + (off & 3)) * 128;

    const int NT = K >> 6;
    const int lr31 = lane & 31;
    const int kh = lane >> 5;

    const unsigned short* Ag[4];
    const unsigned short* Bg[4];
#pragma unroll
    for (int j = 0; j < 4; ++j) {
        const int L = j * 256 + t;
        const int r = L >> 3;
        const int c = ((L & 7) ^ (r & 7)) * 8;
        Ag[j] = A + (size_t)(rowBase + r) * K + c;
        Bg[j] = Bm + (size_t)(colBase + r) * K + c;
    }

    floatx16 acc[2][2] = {};

#pragma unroll
    for (int j = 0; j < 4; ++j) gl_lds16(Ag[j], &lds[0][0][j * 2048 + wid * 512]);
#pragma unroll
    for (int j = 0; j < 4; ++j) gl_lds16(Bg[j], &lds[0][1][j * 2048 + wid * 512]);
#pragma unroll
    for (int j = 0; j < 4; ++j) { Ag[j] += 64; Bg[j] += 64; }

    int cur = 0;
    for (int tt = 0; tt < NT; ++tt) {
        if (tt + 1 < NT) {
#pragma unroll
            for (int j = 0; j < 4; ++j)
                gl_lds16(Ag[j], &lds[cur ^ 1][0][j * 2048 + wid * 512]);
#pragma unroll
            for (int j = 0; j < 4; ++j)
                gl_lds16(Bg[j], &lds[cur ^ 1][1][j * 2048 + wid * 512]);
#pragma unroll
            for (int j = 0; j < 4; ++j) { Ag[j] += 64; Bg[j] += 64; }
            asm volatile("s_waitcnt vmcnt(8)" ::: "memory");
        } else {
            asm volatile("s_waitcnt vmcnt(0)" ::: "memory");
        }
        __builtin_amdgcn_s_barrier();
        __builtin_amdgcn_sched_barrier(0);
        const unsigned short* Ab = &lds[cur][0][0];
        const unsigned short* Bb = &lds[cur][1][0];
#pragma unroll
        for (int ks = 0; ks < 4; ++ks) {
            short8 af[2], bfr[2];
#pragma unroll
            for (int mf = 0; mf < 2; ++mf) {
                const int r = wr * 64 + mf * 32 + lr31;
                const int cp = (ks * 2 + kh) ^ (r & 7);
                af[mf] = *reinterpret_cast<const short8*>(&Ab[r * 64 + cp * 8]);
            }
#pragma unroll
            for (int nf = 0; nf < 2; ++nf) {
                const int r = wc * 64 + nf * 32 + lr31;
                const int cp = (ks * 2 + kh) ^ (r & 7);
                bfr[nf] = *reinterpret_cast<const short8*>(&Bb[r * 64 + cp * 8]);
            }
            __builtin_amdgcn_s_setprio(1);
#pragma unroll
            for (int mf = 0; mf < 2; ++mf)
#pragma unroll
                for (int nf = 0; nf < 2; ++nf)
                    acc[mf][nf] = __builtin_amdgcn_mfma_f32_32x32x16_bf16(af[mf], bfr[nf], acc[mf][nf], 0, 0, 0);
            __builtin_amdgcn_s_setprio(0);
        }
        __builtin_amdgcn_sched_barrier(0);
        __builtin_amdgcn_s_barrier();
        cur ^= 1;
    }

    const int rbw = rowBase + wr * 64;
    const int cbw = colBase + wc * 64;
    const int lc31 = lane & 31;
    if (EPI == 4) {
        unsigned short* qh = (unsigned short*)outp;  // Qh | Kh (+8M) | Vt (+16M)
        const float SC2 = 0.18033688f;               // 0.125*log2(e) folded into Q
#pragma unroll
        for (int nf = 0; nf < 2; ++nf) {
            const int c = cbw + nf * 32 + lc31;
            const float bn = bias[c];
            const int sect = c >> 10;
            const int hh = (c >> 6) & 15;
            const int dd = c & 63;
            const float scl = (sect == 0) ? SC2 : 1.f;
#pragma unroll
            for (int mf = 0; mf < 2; ++mf) {
#pragma unroll
                for (int rg = 0; rg < 4; ++rg) {
                    const int r0 = rbw + mf * 32 + rg * 8 + 4 * kh;
                    const int bb = r0 >> 10, ss = r0 & 1023;
                    if (sect == 2) {
                        short4_t pk;
#pragma unroll
                        for (int j = 0; j < 4; ++j) pk[j] = (short)f2b(acc[mf][nf][rg * 4 + j] + bn);
                        *reinterpret_cast<short4_t*>(
                            &qh[16777216 + ((size_t)((bb * 16 + hh) * 64 + dd)) * 1024 + ss]) = pk;
                    } else {
                        unsigned short* base = qh + sect * 8388608;
#pragma unroll
                        for (int j = 0; j < 4; ++j)
                            base[((size_t)((bb * 16 + hh) * 1024 + ss + j)) * 64 + dd] =
                                f2b((acc[mf][nf][rg * 4 + j] + bn) * scl);
                    }
                }
            }
        }
        return;
    }
#pragma unroll
    for (int nf = 0; nf < 2; ++nf) {
        const int c = cbw + nf * 32 + lc31;
        const float bn = bias[c];
#pragma unroll
        for (int mf = 0; mf < 2; ++mf) {
#pragma unroll
            for (int rg = 0; rg < 4; ++rg) {
#pragma unroll
                for (int j = 0; j < 4; ++j) {
                    const int r = rbw + mf * 32 + rg * 8 + 4 * kh + j;
                    if (EPI == 2) {
                        const float v = acc[mf][nf][rg * 4 + j] + bn +
                                        ((const float*)res)[(size_t)r * N + c];
                        ((unsigned short*)outp)[(size_t)r * N + c] = f2b(v);
                    } else {  // EPI == 5
                        const float v = acc[mf][nf][rg * 4 + j] + bn +
                                        b2f(((const unsigned short*)res)[(size_t)r * N + c]);
                        ((float*)outp)[(size_t)r * N + c] = v;
                    }
                }
            }
        }
    }
}

// ---------------- Phase-pipelined 256x256 NT GEMM (FFN1): bf16 relu(+bias) out ----------------
__global__ __launch_bounds__(512, 2) void gemm256p(const unsigned short* __restrict__ A,
                                                   const unsigned short* __restrict__ Bm,
                                                   const float* __restrict__ bias,
                                                   unsigned short* __restrict__ outp,
                                                   int M, int N, int K, int tilesX) {
    __shared__ __align__(16) unsigned short Abuf[2][16384];
    __shared__ __align__(16) unsigned short Bbuf[2][16384];
    const int t = threadIdx.x;
    const int lane = t & 63, wid = t >> 6;
    const int wr = wid >> 2, wc = wid & 3;

    const int bid = blockIdx.x;
    const int xcd = bid & 7;
    const int lid = bid >> 3;
    const int sid = lid >> 5;
    const int off = lid & 31;
    const int gsid = sid * 8 + xcd;
    const int supercols = tilesX >> 2;
    const int srow = gsid / supercols;
    const int scol = gsid - srow * supercols;
    const int rowBase = (srow * 8 + (off >> 2)) * 256;
    const int colBase = (scol * 4 + (off & 3)) * 256;

    const int NT = K >> 6;
    const int lr31 = lane & 31;
    const int kh = lane >> 5;
    const int x7 = lane & 7;

    const int rho_s = t >> 3;
    const int csrc = ((t & 7) ^ (rho_s & 7)) * 8;
    const int ldst = t * 8;
    const unsigned short* Bs_[2][2];
    const unsigned short* As_[2][2];
#pragma unroll
    for (int h = 0; h < 2; ++h)
#pragma unroll
        for (int j = 0; j < 2; ++j) {
            const int rr = rho_s + j * 64;
            Bs_[h][j] = Bm + (size_t)(colBase + h * 128 + rr) * K + csrc;
            As_[h][j] = A + (size_t)(rowBase + ((rr >> 6) * 128 + h * 64 + (rr & 63))) * K + csrc;
        }

#define STG_BH(h_, b_, kk_)                                                   \
    do {                                                                      \
        gl_lds16(Bs_[h_][0] + (kk_), &Bbuf[b_][(h_)*8192 + ldst]);            \
        gl_lds16(Bs_[h_][1] + (kk_), &Bbuf[b_][(h_)*8192 + 4096 + ldst]);     \
    } while (0)
#define STG_AH(h_, b_, kk_)                                                   \
    do {                                                                      \
        gl_lds16(As_[h_][0] + (kk_), &Abuf[b_][(h_)*8192 + ldst]);            \
        gl_lds16(As_[h_][1] + (kk_), &Abuf[b_][(h_)*8192 + 4096 + ldst]);     \
    } while (0)

    floatx16 acc[4][2] = {};

    STG_BH(0, 0, 0); STG_BH(1, 0, 0); STG_AH(0, 0, 0); STG_AH(1, 0, 0);
    asm volatile("s_waitcnt vmcnt(0)" ::: "memory");
    __builtin_amdgcn_s_barrier();

    for (int kt = 0; kt < NT; ++kt) {
        const int cur = kt & 1, nxt = cur ^ 1;
        const bool pf = (kt + 1 < NT);
        const int kkn = (pf ? kt + 1 : kt) << 6;
        short8 bfr[2][4];
#pragma unroll
        for (int q = 0; q < 4; ++q) {
            short8 af[4];
            {
                const int rho = wr * 64 + (q & 1) * 32 + lr31;
                const unsigned short* Ab = &Abuf[cur][(q >> 1) * 8192];
#pragma unroll
                for (int s = 0; s < 4; ++s)
                    af[s] = *reinterpret_cast<const short8*>(
                        &Ab[rho * 64 + ((2 * s + kh) ^ x7) * 8]);
            }
            if (q == 0) {
#pragma unroll
                for (int nf = 0; nf < 2; ++nf) {
                    const int gcol = wc * 64 + nf * 32 + lr31;
                    const unsigned short* Bb = &Bbuf[cur][(gcol >> 7) * 8192];
                    const int rho = gcol & 127;
#pragma unroll
                    for (int s = 0; s < 4; ++s)
                        bfr[nf][s] = *reinterpret_cast<const short8*>(
                            &Bb[rho * 64 + ((2 * s + kh) ^ x7) * 8]);
                }
            }
            if (pf) {
                if (q == 0) STG_BH(0, nxt, kkn);
                if (q == 1) STG_BH(1, nxt, kkn);
                if (q == 2) STG_AH(0, nxt, kkn);
                if (q == 3) STG_AH(1, nxt, kkn);
            }
            __builtin_amdgcn_s_barrier();
            asm volatile("s_waitcnt lgkmcnt(0)" ::: "memory");
            __builtin_amdgcn_sched_barrier(0);
            __builtin_amdgcn_s_setprio(1);
#pragma unroll
            for (int s = 0; s < 4; ++s)
#pragma unroll
                for (int nf = 0; nf < 2; ++nf)
                    acc[q][nf] = __builtin_amdgcn_mfma_f32_32x32x16_bf16(af[s], bfr[nf][s], acc[q][nf], 0, 0, 0);
            __builtin_amdgcn_s_setprio(0);
            __builtin_amdgcn_sched_barrier(0);
            if (q == 1) {
                if (pf) asm volatile("s_waitcnt vmcnt(4)" ::: "memory");
                else    asm volatile("s_waitcnt vmcnt(0)" ::: "memory");
            }
            if (q == 3 && pf) asm volatile("s_waitcnt vmcnt(2)" ::: "memory");
            __builtin_amdgcn_s_barrier();
        }
    }
#undef STG_AH
#undef STG_BH

    const int rbw = rowBase + wr * 128;
    const int cbw = colBase + wc * 64;
    const int lc31 = lane & 31;
#pragma unroll
    for (int nf = 0; nf < 2; ++nf) {
        const int c = cbw + nf * 32 + lc31;
        const float bn = bias[c];
#pragma unroll
        for (int q = 0; q < 4; ++q) {
#pragma unroll
            for (int rg = 0; rg < 4; ++rg) {
                const int r0 = rbw + q * 32 + rg * 8 + 4 * kh;
#pragma unroll
                for (int j = 0; j < 4; ++j) {
                    const float v = fmaxf(acc[q][nf][rg * 4 + j] + bn, 0.f);
                    outp[(size_t)(r0 + j) * N + c] = f2b(v);
                }
            }
        }
    }
}

// ---------------- MFMA flash attention: no-max exact softmax, mask-gated bias ----------------
__global__ __launch_bounds__(256) void attn_mfma(const unsigned short* __restrict__ Qh,
                                                 const unsigned short* __restrict__ Kh,
                                                 const unsigned short* __restrict__ Vt,
                                                 const float* __restrict__ mbias,
                                                 const int* __restrict__ mflags,
                                                 unsigned short* __restrict__ out) {
    __shared__ __align__(16) unsigned short Kbuf[2][4096];
    __shared__ __align__(16) unsigned short Vbuf[2][4096];
    __shared__ __align__(16) unsigned short Pbuf[4][16][72];
    __shared__ __align__(16) float mk[1024];
    const int t = threadIdx.x;
    const int w = t >> 6, l = t & 63;
    const int g = l >> 4, q16 = l & 15;
    const int x7 = q16 & 7;
    const int bid = blockIdx.x;
    const int swz = (bid & 7) * 256 + (bid >> 3);
    const int bh = swz >> 4, qb = swz & 15;
    const int b = bh >> 4, h = bh & 15;

    const size_t qbase = ((size_t)bh * 1024 + qb * 64 + w * 16 + q16) * 64;
    const short8 qf0 = *reinterpret_cast<const short8*>(Qh + qbase + g * 8);
    const short8 qf1 = *reinterpret_cast<const short8*>(Qh + qbase + 32 + g * 8);

    const int r0 = t >> 3;
    const int c0 = ((t & 7) ^ (r0 & 7)) * 8;
    const unsigned short* Kg = Kh + (size_t)bh * 65536 + r0 * 64 + c0;
    const unsigned short* Vg = Vt + (size_t)bh * 65536 + r0 * 1024 + c0;

#define ATTN_STAGE(bi, kc_)                                                        \
    do {                                                                           \
        gl_lds16(Kg + (kc_) * 4096, &Kbuf[bi][w * 512]);                           \
        gl_lds16(Kg + (kc_) * 4096 + 2048, &Kbuf[bi][2048 + w * 512]);             \
        gl_lds16(Vg + (kc_) * 64, &Vbuf[bi][w * 512]);                             \
        gl_lds16(Vg + (kc_) * 64 + 32768, &Vbuf[bi][2048 + w * 512]);              \
    } while (0)

    gl_lds16(mbias + b * 1024 + t * 4, &mk[w * 256]);
    ATTN_STAGE(0, 0);

    floatx4 oacc[4] = {};
    floatx4 loacc = {};
    short8 ones;
#pragma unroll
    for (int j = 0; j < 8; ++j) ones[j] = (short)0x3F80;  // bf16 1.0

    int cur = 0;
    for (int kc = 0; kc < 16; ++kc) {
        if (kc < 15) {
            ATTN_STAGE(cur ^ 1, kc + 1);
            asm volatile("s_waitcnt vmcnt(4)" ::: "memory");
        } else {
            asm volatile("s_waitcnt vmcnt(0)" ::: "memory");
        }
        __builtin_amdgcn_s_barrier();
        __builtin_amdgcn_sched_barrier(0);
        const unsigned short* Kb = Kbuf[cur];
        const unsigned short* Vb = Vbuf[cur];

        floatx4 st[4] = {};
        __builtin_amdgcn_s_setprio(1);
#pragma unroll
        for (int t4 = 0; t4 < 4; ++t4) {
            const int row = t4 * 16 + q16;
            const short8 kf0 = *reinterpret_cast<const short8*>(&Kb[row * 64 + (g ^ x7) * 8]);
            const short8 kf1 = *reinterpret_cast<const short8*>(&Kb[row * 64 + ((4 + g) ^ x7) * 8]);
            st[t4] = __builtin_amdgcn_mfma_f32_16x16x32_bf16(kf0, qf0, st[t4], 0, 0, 0);
            st[t4] = __builtin_amdgcn_mfma_f32_16x16x32_bf16(kf1, qf1, st[t4], 0, 0, 0);
        }
        __builtin_amdgcn_s_setprio(0);

        if (mflags[b * 16 + kc]) {
#pragma unroll
            for (int t4 = 0; t4 < 4; ++t4) {
                const float4 mbv = *reinterpret_cast<const float4*>(&mk[kc * 64 + t4 * 16 + g * 4]);
#pragma unroll
                for (int r = 0; r < 4; ++r) st[t4][r] += ((const float*)&mbv)[r];
            }
        }
#pragma unroll
        for (int t4 = 0; t4 < 4; ++t4) {
            const float p0 = __builtin_exp2f(st[t4][0]);
            const float p1 = __builtin_exp2f(st[t4][1]);
            const float p2 = __builtin_exp2f(st[t4][2]);
            const float p3 = __builtin_exp2f(st[t4][3]);
            unsigned u0, u1;
            asm("v_cvt_pk_bf16_f32 %0, %1, %2" : "=v"(u0) : "v"(p0), "v"(p1));
            asm("v_cvt_pk_bf16_f32 %0, %1, %2" : "=v"(u1) : "v"(p2), "v"(p3));
            uint2 pr; pr.x = u0; pr.y = u1;
            *reinterpret_cast<uint2*>(&Pbuf[w][q16][t4 * 16 + g * 4]) = pr;
        }

        const short8 pf0 = *reinterpret_cast<const short8*>(&Pbuf[w][q16][g * 8]);
        const short8 pf1 = *reinterpret_cast<const short8*>(&Pbuf[w][q16][32 + g * 8]);
        __builtin_amdgcn_s_setprio(1);
        loacc = __builtin_amdgcn_mfma_f32_16x16x32_bf16(pf0, ones, loacc, 0, 0, 0);
        loacc = __builtin_amdgcn_mfma_f32_16x16x32_bf16(pf1, ones, loacc, 0, 0, 0);
#pragma unroll
        for (int n = 0; n < 4; ++n) {
            const int row = n * 16 + q16;
            const short8 vf0 = *reinterpret_cast<const short8*>(&Vb[row * 64 + (g ^ x7) * 8]);
            const short8 vf1 = *reinterpret_cast<const short8*>(&Vb[row * 64 + ((4 + g) ^ x7) * 8]);
            oacc[n] = __builtin_amdgcn_mfma_f32_16x16x32_bf16(pf0, vf0, oacc[n], 0, 0, 0);
            oacc[n] = __builtin_amdgcn_mfma_f32_16x16x32_bf16(pf1, vf1, oacc[n], 0, 0, 0);
        }
        __builtin_amdgcn_s_setprio(0);
        __builtin_amdgcn_sched_barrier(0);
        __builtin_amdgcn_s_barrier();
        cur ^= 1;
    }
#undef ATTN_STAGE

    const size_t obase = ((size_t)b * S_ + qb * 64 + w * 16) * 1024 + h * 64;
#pragma unroll
    for (int r = 0; r < 4; ++r) {
        const float invr = 1.f / loacc[r];
        const size_t orow = obase + (size_t)(g * 4 + r) * 1024;
#pragma unroll
        for (int n = 0; n < 4; ++n)
            out[orow + n * 16 + q16] = f2b(oacc[n][r] * invr);
    }
}

extern "C" void kernel_launch(void* const* d_in, const int* in_sizes, int n_in,
                              void* d_out, int out_size, void* d_ws, size_t ws_size,
                              hipStream_t stream) {
    const float* x   = (const float*)d_in[0];
    const int*  mask = (const int*)d_in[1];
    const float* wq  = (const float*)d_in[2];
    const float* bq  = (const float*)d_in[3];
    const float* wk  = (const float*)d_in[4];
    const float* bk  = (const float*)d_in[5];
    const float* wv  = (const float*)d_in[6];
    const float* bv  = (const float*)d_in[7];
    const float* wo  = (const float*)d_in[8];
    const float* bo  = (const float*)d_in[9];
    const float* w1  = (const float*)d_in[10];
    const float* b1  = (const float*)d_in[11];
    const float* w2  = (const float*)d_in[12];
    const float* b2  = (const float*)d_in[13];
    const float* g1  = (const float*)d_in[14];
    const float* be1 = (const float*)d_in[15];
    const float* g2  = (const float*)d_in[16];
    const float* be2 = (const float*)d_in[17];

    char* ws = (char*)d_ws;
    unsigned short* wqkv_bf = (unsigned short*)(ws);                 // 6 MB
    unsigned short* wo_bf   = (unsigned short*)(ws + 6291456);       // 2 MB
    unsigned short* w1_bf   = (unsigned short*)(ws + 8388608);       // 8 MB
    unsigned short* w2_bf   = (unsigned short*)(ws + 16777216);      // 8 MB
    float*          bqkv    = (float*)(ws + 25165824);               // 12 KB
    float*          mbias   = (float*)(ws + 25178112);               // 32 KB
    int*            mflags  = (int*)(ws + 25210880);                 // 512 B
    unsigned short* h_bf    = (unsigned short*)(ws + 25214976);      // 16 MB
    unsigned short* x1b     = (unsigned short*)(ws + 41992192);      // 16 MB (bf16 x1)
    unsigned short* attn_bf = (unsigned short*)(ws + 75546624);      // 16 MB
    unsigned short* qkvh    = (unsigned short*)(ws + 92323840);      // 48 MB: Qh|Kh|Vt
    unsigned short* ff1_bf  = (unsigned short*)(ws + 92323840);      // 64 MB (overlays qkvh after attn)

    // fused preprocessing + LN1: ONE launch
    prep_kernel<<<20482, 256, 0, stream>>>(wq, wk, wv, wo, w1, w2, bq, bk, bv, mask,
                                           x, g1, be1,
                                           wqkv_bf, wo_bf, w1_bf, w2_bf, bqkv, mbias, mflags, h_bf);

    // QKV projection (128² tiles: 24 x 64), scatter to Qh/Kh/Vt, Q pre-scaled
    gemm_bt<4><<<24 * 64, 256, 0, stream>>>(h_bf, wqkv_bf, bqkv, nullptr, qkvh, NTOK, 3072, 1024, 24);
    // flash attention (no-max exact softmax, mask-gated)
    attn_mfma<<<2048, 256, 0, stream>>>(qkvh, qkvh + 8388608, qkvh + 16777216, mbias, mflags, attn_bf);
    // O-projection + residual -> bf16 x1b (128² tiles: 8 x 64)
    gemm_bt<2><<<8 * 64, 256, 0, stream>>>(attn_bf, wo_bf, bo, x, x1b, NTOK, 1024, 1024, 8);
    // LN2 (bf16 input)
    ln_bf16<<<NTOK, 256, 0, stream>>>(x1b, g2, be2, h_bf);
    // FFN1 + ReLU (phase-pipelined 256² tiles: 32 x 16 = 512 blocks)
    gemm256p<<<512, 512, 0, stream>>>(h_bf, w1_bf, b1, ff1_bf, NTOK, 4096, 1024, 16);
    // FFN2 + bf16 residual -> fp32 out (128² tiles: 8 x 64)
    gemm_bt<5><<<8 * 64, 256, 0, stream>>>(ff1_bf, w2_bf, b2, x1b, (float*)d_out, NTOK, 1024, 4096, 8);
}

// Round 22
// 345.744 us; speedup vs baseline: 1.0555x; 1.0317x over previous
//
#include <hip/hip_runtime.h>

typedef __attribute__((ext_vector_type(8))) short short8;
typedef __attribute__((ext_vector_type(4))) short short4_t;
typedef __attribute__((ext_vector_type(4))) float floatx4;
typedef __attribute__((ext_vector_type(16))) float floatx16;

#define NTOK 8192
#define S_ 1024
#define DM 1024

__device__ __forceinline__ unsigned short f2b(float f) {
    union { float f; unsigned u; } v; v.f = f;
    unsigned r = v.u + 0x7FFF + ((v.u >> 16) & 1);
    return (unsigned short)(r >> 16);
}

__device__ __forceinline__ float b2f(unsigned short u) {
    union { unsigned u; float f; } v; v.u = ((unsigned)u) << 16;
    return v.f;
}

__device__ __forceinline__ void gl_lds16(const void* g, void* l) {
    __builtin_amdgcn_global_load_lds((const __attribute__((address_space(1))) void*)g,
                                     (__attribute__((address_space(3))) void*)l, 16, 0, 0);
}

// ---------------- fused preprocessing + LN1, ONE launch ----------------
// blocks 0..12287: weight fp32->bf16 (1 quad/thread)
// block 12288: bqkv copy; block 12289: mbias + mflags; blocks 12290..20481: LN1 rows
__global__ __launch_bounds__(256) void prep_kernel(const float* __restrict__ wq,
                                                   const float* __restrict__ wk,
                                                   const float* __restrict__ wv,
                                                   const float* __restrict__ wo,
                                                   const float* __restrict__ w1,
                                                   const float* __restrict__ w2,
                                                   const float* __restrict__ bq,
                                                   const float* __restrict__ bk,
                                                   const float* __restrict__ bv,
                                                   const int* __restrict__ mask,
                                                   const float* __restrict__ x,
                                                   const float* __restrict__ g1,
                                                   const float* __restrict__ be1,
                                                   unsigned short* __restrict__ wqkv_bf,
                                                   unsigned short* __restrict__ wo_bf,
                                                   unsigned short* __restrict__ w1_bf,
                                                   unsigned short* __restrict__ w2_bf,
                                                   float* __restrict__ bqkv,
                                                   float* __restrict__ mbias,
                                                   int* __restrict__ mflags,
                                                   unsigned short* __restrict__ h_bf) {
    const int bid = blockIdx.x;
    const int t = threadIdx.x;
    if (bid < 12288) {
        const int q = bid * 256 + t;
        const float* src;
        unsigned short* dst;
        int lq;
        if (q < 786432) {            // wq|wk|wv -> wqkv_bf (contiguous layout)
            src = (q < 262144) ? wq : (q < 524288 ? wk : wv);
            lq = q & 262143;
            dst = wqkv_bf + (size_t)(q >> 18) * 1048576;
        } else if (q < 1048576) {
            src = wo; lq = q - 786432; dst = wo_bf;
        } else if (q < 2097152) {
            src = w1; lq = q - 1048576; dst = w1_bf;
        } else {
            src = w2; lq = q - 2097152; dst = w2_bf;
        }
        const float4 v = *reinterpret_cast<const float4*>(src + (size_t)lq * 4);
        short4_t o;
        o.x = (short)f2b(v.x); o.y = (short)f2b(v.y);
        o.z = (short)f2b(v.z); o.w = (short)f2b(v.w);
        *reinterpret_cast<short4_t*>(dst + (size_t)lq * 4) = o;
        return;
    }
    if (bid == 12288) {
#pragma unroll
        for (int it = 0; it < 3; ++it) {
            const int q = t + it * 256;
            const float* src = (q < 256) ? bq : (q < 512 ? bk : bv);
            const int lq = q & 255;
            *reinterpret_cast<float4*>(bqkv + q * 4) =
                *reinterpret_cast<const float4*>(src + lq * 4);
        }
        return;
    }
    if (bid == 12289) {
#pragma unroll
        for (int it = 0; it < 8; ++it) {
            const int q = t + it * 256;
            const int4 m = *reinterpret_cast<const int4*>(mask + q * 4);
            float4 o;
            o.x = (m.x == 0) ? -1e9f : 0.f;
            o.y = (m.y == 0) ? -1e9f : 0.f;
            o.z = (m.z == 0) ? -1e9f : 0.f;
            o.w = (m.w == 0) ? -1e9f : 0.f;
            *reinterpret_cast<float4*>(mbias + q * 4) = o;
        }
        if (t < 128) {
            int f = 0;
            const int* mp = mask + t * 64;
#pragma unroll
            for (int k = 0; k < 64; ++k) f |= (mp[k] == 0) ? 1 : 0;
            mflags[t] = f;
        }
        return;
    }
    // LN1 rows
    const int row = bid - 12290;
    const float4 xv = *reinterpret_cast<const float4*>(x + (size_t)row * DM + t * 4);
    float s = xv.x + xv.y + xv.z + xv.w;
#pragma unroll
    for (int off = 32; off > 0; off >>= 1) s += __shfl_down(s, off);
    __shared__ float red[8];
    const int wid = t >> 6, lane = t & 63;
    if (lane == 0) red[wid] = s;
    __syncthreads();
    const float mean = (red[0] + red[1] + red[2] + red[3]) * (1.f / 1024.f);
    const float dx = xv.x - mean, dy = xv.y - mean, dz = xv.z - mean, dw = xv.w - mean;
    float ss = dx * dx + dy * dy + dz * dz + dw * dw;
#pragma unroll
    for (int off = 32; off > 0; off >>= 1) ss += __shfl_down(ss, off);
    if (lane == 0) red[4 + wid] = ss;
    __syncthreads();
    const float var = (red[4] + red[5] + red[6] + red[7]) * (1.f / 1023.f);
    const float inv = 1.f / (sqrtf(var) + 1e-6f);
    const float4 gv = *reinterpret_cast<const float4*>(g1 + t * 4);
    const float4 bev = *reinterpret_cast<const float4*>(be1 + t * 4);
    short4_t o;
    o.x = (short)f2b(gv.x * dx * inv + bev.x);
    o.y = (short)f2b(gv.y * dy * inv + bev.y);
    o.z = (short)f2b(gv.z * dz * inv + bev.z);
    o.w = (short)f2b(gv.w * dw * inv + bev.w);
    *reinterpret_cast<short4_t*>(h_bf + (size_t)row * DM + t * 4) = o;
}

// ---------------- LayerNorm over bf16 input (LN2), out bf16 ----------------
__global__ __launch_bounds__(256) void ln_bf16(const unsigned short* __restrict__ xb,
                                               const float* __restrict__ g,
                                               const float* __restrict__ be,
                                               unsigned short* __restrict__ out) {
    const int row = blockIdx.x;
    const int t = threadIdx.x;
    const short4_t xv4 = *reinterpret_cast<const short4_t*>(xb + (size_t)row * DM + t * 4);
    float xv[4];
#pragma unroll
    for (int j = 0; j < 4; ++j) xv[j] = b2f((unsigned short)xv4[j]);
    float s = xv[0] + xv[1] + xv[2] + xv[3];
#pragma unroll
    for (int off = 32; off > 0; off >>= 1) s += __shfl_down(s, off);
    __shared__ float red[8];
    const int wid = t >> 6, lane = t & 63;
    if (lane == 0) red[wid] = s;
    __syncthreads();
    const float mean = (red[0] + red[1] + red[2] + red[3]) * (1.f / 1024.f);
    float d[4];
#pragma unroll
    for (int j = 0; j < 4; ++j) d[j] = xv[j] - mean;
    float ss = d[0] * d[0] + d[1] * d[1] + d[2] * d[2] + d[3] * d[3];
#pragma unroll
    for (int off = 32; off > 0; off >>= 1) ss += __shfl_down(ss, off);
    if (lane == 0) red[4 + wid] = ss;
    __syncthreads();
    const float var = (red[4] + red[5] + red[6] + red[7]) * (1.f / 1023.f);
    const float inv = 1.f / (sqrtf(var) + 1e-6f);
    const float4 gv = *reinterpret_cast<const float4*>(g + t * 4);
    const float4 bev = *reinterpret_cast<const float4*>(be + t * 4);
    short4_t o;
    o.x = (short)f2b(gv.x * d[0] * inv + bev.x);
    o.y = (short)f2b(gv.y * d[1] * inv + bev.y);
    o.z = (short)f2b(gv.z * d[2] * inv + bev.z);
    o.w = (short)f2b(gv.w * d[3] * inv + bev.w);
    *reinterpret_cast<short4_t*>(out + (size_t)row * DM + t * 4) = o;
}

// ---------------- 128x128 NT GEMM, bf16 in, fp32 acc, 32x32x16 MFMA ----------------
// EPI: 2 = bf16 out (+bias + fp32 residual)  [O-proj -> x1b]
//      4 = QKV scatter (Qh pre-scaled | Kh | Vt)
//      5 = fp32 out (+bias + bf16 residual)  [FFN2 -> d_out]
template <int EPI>
__global__ __launch_bounds__(256, 2) void gemm_bt(const unsigned short* __restrict__ A,
                                                  const unsigned short* __restrict__ Bm,
                                                  const float* __restrict__ bias,
                                                  const void* __restrict__ res,
                                                  void* __restrict__ outp,
                                                  int M, int N, int K, int tilesX) {
    __shared__ __align__(16) unsigned short lds[2][2][8192];
    const int t = threadIdx.x;
    const int lane = t & 63, wid = t >> 6;
    const int wr = wid >> 1, wc = wid & 1;

    const int bid = blockIdx.x;
    const int xcd = bid & 7;
    const int lid = bid >> 3;
    const int sid = lid >> 5;
    const int off = lid & 31;
    const int gsid = sid * 8 + xcd;
    const int supercols = tilesX >> 2;
    const int srow = gsid / supercols;
    const int scol = gsid - srow * supercols;
    const int rowBase = (srow * 8 + (off >> 2)) * 128;
    const int colBase = (scol * 4 + (off & 3)) * 128;

    const int NT = K >> 6;
    const int lr31 = lane & 31;
    const int kh = lane >> 5;

    const unsigned short* Ag[4];
    const unsigned short* Bg[4];
#pragma unroll
    for (int j = 0; j < 4; ++j) {
        const int L = j * 256 + t;
        const int r = L >> 3;
        const int c = ((L & 7) ^ (r & 7)) * 8;
        Ag[j] = A + (size_t)(rowBase + r) * K + c;
        Bg[j] = Bm + (size_t)(colBase + r) * K + c;
    }

    floatx16 acc[2][2] = {};

#pragma unroll
    for (int j = 0; j < 4; ++j) gl_lds16(Ag[j], &lds[0][0][j * 2048 + wid * 512]);
#pragma unroll
    for (int j = 0; j < 4; ++j) gl_lds16(Bg[j], &lds[0][1][j * 2048 + wid * 512]);
#pragma unroll
    for (int j = 0; j < 4; ++j) { Ag[j] += 64; Bg[j] += 64; }

    int cur = 0;
    for (int tt = 0; tt < NT; ++tt) {
        if (tt + 1 < NT) {
#pragma unroll
            for (int j = 0; j < 4; ++j)
                gl_lds16(Ag[j], &lds[cur ^ 1][0][j * 2048 + wid * 512]);
#pragma unroll
            for (int j = 0; j < 4; ++j)
                gl_lds16(Bg[j], &lds[cur ^ 1][1][j * 2048 + wid * 512]);
#pragma unroll
            for (int j = 0; j < 4; ++j) { Ag[j] += 64; Bg[j] += 64; }
            asm volatile("s_waitcnt vmcnt(8)" ::: "memory");
        } else {
            asm volatile("s_waitcnt vmcnt(0)" ::: "memory");
        }
        __builtin_amdgcn_s_barrier();
        __builtin_amdgcn_sched_barrier(0);
        const unsigned short* Ab = &lds[cur][0][0];
        const unsigned short* Bb = &lds[cur][1][0];
#pragma unroll
        for (int ks = 0; ks < 4; ++ks) {
            short8 af[2], bfr[2];
#pragma unroll
            for (int mf = 0; mf < 2; ++mf) {
                const int r = wr * 64 + mf * 32 + lr31;
                const int cp = (ks * 2 + kh) ^ (r & 7);
                af[mf] = *reinterpret_cast<const short8*>(&Ab[r * 64 + cp * 8]);
            }
#pragma unroll
            for (int nf = 0; nf < 2; ++nf) {
                const int r = wc * 64 + nf * 32 + lr31;
                const int cp = (ks * 2 + kh) ^ (r & 7);
                bfr[nf] = *reinterpret_cast<const short8*>(&Bb[r * 64 + cp * 8]);
            }
            __builtin_amdgcn_s_setprio(1);
#pragma unroll
            for (int mf = 0; mf < 2; ++mf)
#pragma unroll
                for (int nf = 0; nf < 2; ++nf)
                    acc[mf][nf] = __builtin_amdgcn_mfma_f32_32x32x16_bf16(af[mf], bfr[nf], acc[mf][nf], 0, 0, 0);
            __builtin_amdgcn_s_setprio(0);
        }
        __builtin_amdgcn_sched_barrier(0);
        __builtin_amdgcn_s_barrier();
        cur ^= 1;
    }

    const int rbw = rowBase + wr * 64;
    const int cbw = colBase + wc * 64;
    const int lc31 = lane & 31;
    if (EPI == 4) {
        unsigned short* qh = (unsigned short*)outp;  // Qh | Kh (+8M) | Vt (+16M)
        const float SC2 = 0.18033688f;               // 0.125*log2(e) folded into Q
#pragma unroll
        for (int nf = 0; nf < 2; ++nf) {
            const int c = cbw + nf * 32 + lc31;
            const float bn = bias[c];
            const int sect = c >> 10;
            const int hh = (c >> 6) & 15;
            const int dd = c & 63;
            const float scl = (sect == 0) ? SC2 : 1.f;
#pragma unroll
            for (int mf = 0; mf < 2; ++mf) {
#pragma unroll
                for (int rg = 0; rg < 4; ++rg) {
                    const int r0 = rbw + mf * 32 + rg * 8 + 4 * kh;
                    const int bb = r0 >> 10, ss = r0 & 1023;
                    if (sect == 2) {
                        short4_t pk;
#pragma unroll
                        for (int j = 0; j < 4; ++j) pk[j] = (short)f2b(acc[mf][nf][rg * 4 + j] + bn);
                        *reinterpret_cast<short4_t*>(
                            &qh[16777216 + ((size_t)((bb * 16 + hh) * 64 + dd)) * 1024 + ss]) = pk;
                    } else {
                        unsigned short* base = qh + sect * 8388608;
#pragma unroll
                        for (int j = 0; j < 4; ++j)
                            base[((size_t)((bb * 16 + hh) * 1024 + ss + j)) * 64 + dd] =
                                f2b((acc[mf][nf][rg * 4 + j] + bn) * scl);
                    }
                }
            }
        }
        return;
    }
#pragma unroll
    for (int nf = 0; nf < 2; ++nf) {
        const int c = cbw + nf * 32 + lc31;
        const float bn = bias[c];
#pragma unroll
        for (int mf = 0; mf < 2; ++mf) {
#pragma unroll
            for (int rg = 0; rg < 4; ++rg) {
#pragma unroll
                for (int j = 0; j < 4; ++j) {
                    const int r = rbw + mf * 32 + rg * 8 + 4 * kh + j;
                    if (EPI == 2) {
                        const float v = acc[mf][nf][rg * 4 + j] + bn +
                                        ((const float*)res)[(size_t)r * N + c];
                        ((unsigned short*)outp)[(size_t)r * N + c] = f2b(v);
                    } else {  // EPI == 5
                        const float v = acc[mf][nf][rg * 4 + j] + bn +
                                        b2f(((const unsigned short*)res)[(size_t)r * N + c]);
                        ((float*)outp)[(size_t)r * N + c] = v;
                    }
                }
            }
        }
    }
}

// ---------------- Phase-pipelined 256x256 NT GEMM (FFN1): bf16 relu(+bias) out ----------------
__global__ __launch_bounds__(512, 2) void gemm256p(const unsigned short* __restrict__ A,
                                                   const unsigned short* __restrict__ Bm,
                                                   const float* __restrict__ bias,
                                                   unsigned short* __restrict__ outp,
                                                   int M, int N, int K, int tilesX) {
    __shared__ __align__(16) unsigned short Abuf[2][16384];
    __shared__ __align__(16) unsigned short Bbuf[2][16384];
    const int t = threadIdx.x;
    const int lane = t & 63, wid = t >> 6;
    const int wr = wid >> 2, wc = wid & 3;

    const int bid = blockIdx.x;
    const int xcd = bid & 7;
    const int lid = bid >> 3;
    const int sid = lid >> 5;
    const int off = lid & 31;
    const int gsid = sid * 8 + xcd;
    const int supercols = tilesX >> 2;
    const int srow = gsid / supercols;
    const int scol = gsid - srow * supercols;
    const int rowBase = (srow * 8 + (off >> 2)) * 256;
    const int colBase = (scol * 4 + (off & 3)) * 256;

    const int NT = K >> 6;
    const int lr31 = lane & 31;
    const int kh = lane >> 5;
    const int x7 = lane & 7;

    const int rho_s = t >> 3;
    const int csrc = ((t & 7) ^ (rho_s & 7)) * 8;
    const int ldst = t * 8;
    const unsigned short* Bs_[2][2];
    const unsigned short* As_[2][2];
#pragma unroll
    for (int h = 0; h < 2; ++h)
#pragma unroll
        for (int j = 0; j < 2; ++j) {
            const int rr = rho_s + j * 64;
            Bs_[h][j] = Bm + (size_t)(colBase + h * 128 + rr) * K + csrc;
            As_[h][j] = A + (size_t)(rowBase + ((rr >> 6) * 128 + h * 64 + (rr & 63))) * K + csrc;
        }

#define STG_BH(h_, b_, kk_)                                                   \
    do {                                                                      \
        gl_lds16(Bs_[h_][0] + (kk_), &Bbuf[b_][(h_)*8192 + ldst]);            \
        gl_lds16(Bs_[h_][1] + (kk_), &Bbuf[b_][(h_)*8192 + 4096 + ldst]);     \
    } while (0)
#define STG_AH(h_, b_, kk_)                                                   \
    do {                                                                      \
        gl_lds16(As_[h_][0] + (kk_), &Abuf[b_][(h_)*8192 + ldst]);            \
        gl_lds16(As_[h_][1] + (kk_), &Abuf[b_][(h_)*8192 + 4096 + ldst]);     \
    } while (0)

    floatx16 acc[4][2] = {};

    STG_BH(0, 0, 0); STG_BH(1, 0, 0); STG_AH(0, 0, 0); STG_AH(1, 0, 0);
    asm volatile("s_waitcnt vmcnt(0)" ::: "memory");
    __builtin_amdgcn_s_barrier();

    for (int kt = 0; kt < NT; ++kt) {
        const int cur = kt & 1, nxt = cur ^ 1;
        const bool pf = (kt + 1 < NT);
        const int kkn = (pf ? kt + 1 : kt) << 6;
        short8 bfr[2][4];
#pragma unroll
        for (int q = 0; q < 4; ++q) {
            short8 af[4];
            {
                const int rho = wr * 64 + (q & 1) * 32 + lr31;
                const unsigned short* Ab = &Abuf[cur][(q >> 1) * 8192];
#pragma unroll
                for (int s = 0; s < 4; ++s)
                    af[s] = *reinterpret_cast<const short8*>(
                        &Ab[rho * 64 + ((2 * s + kh) ^ x7) * 8]);
            }
            if (q == 0) {
#pragma unroll
                for (int nf = 0; nf < 2; ++nf) {
                    const int gcol = wc * 64 + nf * 32 + lr31;
                    const unsigned short* Bb = &Bbuf[cur][(gcol >> 7) * 8192];
                    const int rho = gcol & 127;
#pragma unroll
                    for (int s = 0; s < 4; ++s)
                        bfr[nf][s] = *reinterpret_cast<const short8*>(
                            &Bb[rho * 64 + ((2 * s + kh) ^ x7) * 8]);
                }
            }
            if (pf) {
                if (q == 0) STG_BH(0, nxt, kkn);
                if (q == 1) STG_BH(1, nxt, kkn);
                if (q == 2) STG_AH(0, nxt, kkn);
                if (q == 3) STG_AH(1, nxt, kkn);
            }
            __builtin_amdgcn_s_barrier();
            asm volatile("s_waitcnt lgkmcnt(0)" ::: "memory");
            __builtin_amdgcn_sched_barrier(0);
            __builtin_amdgcn_s_setprio(1);
#pragma unroll
            for (int s = 0; s < 4; ++s)
#pragma unroll
                for (int nf = 0; nf < 2; ++nf)
                    acc[q][nf] = __builtin_amdgcn_mfma_f32_32x32x16_bf16(af[s], bfr[nf][s], acc[q][nf], 0, 0, 0);
            __builtin_amdgcn_s_setprio(0);
            __builtin_amdgcn_sched_barrier(0);
            if (q == 1) {
                if (pf) asm volatile("s_waitcnt vmcnt(4)" ::: "memory");
                else    asm volatile("s_waitcnt vmcnt(0)" ::: "memory");
            }
            if (q == 3 && pf) asm volatile("s_waitcnt vmcnt(2)" ::: "memory");
            __builtin_amdgcn_s_barrier();
        }
    }
#undef STG_AH
#undef STG_BH

    const int rbw = rowBase + wr * 128;
    const int cbw = colBase + wc * 64;
    const int lc31 = lane & 31;
#pragma unroll
    for (int nf = 0; nf < 2; ++nf) {
        const int c = cbw + nf * 32 + lc31;
        const float bn = bias[c];
#pragma unroll
        for (int q = 0; q < 4; ++q) {
#pragma unroll
            for (int rg = 0; rg < 4; ++rg) {
                const int r0 = rbw + q * 32 + rg * 8 + 4 * kh;
#pragma unroll
                for (int j = 0; j < 4; ++j) {
                    const float v = fmaxf(acc[q][nf][rg * 4 + j] + bn, 0.f);
                    outp[(size_t)(r0 + j) * N + c] = f2b(v);
                }
            }
        }
    }
}

// ---------------- MFMA flash attention: 8 waves / 2 q-blocks sharing K/V ----------------
// 1D grid 1024 (XCD-swizzled), 512 threads. Waves 0-3 -> qblock 2*qpair, waves 4-7 ->
// 2*qpair+1; both share one K/V double-buffer (staged by all 512 threads: 1 load each
// for K and V per chunk). Mask bias read from global under mflags (rarely taken).
// vmcnt FIFO: steady vmcnt(2) (only just-issued next-chunk K+V in flight), last vmcnt(0).
__global__ __launch_bounds__(512) void attn_mfma(const unsigned short* __restrict__ Qh,
                                                 const unsigned short* __restrict__ Kh,
                                                 const unsigned short* __restrict__ Vt,
                                                 const float* __restrict__ mbias,
                                                 const int* __restrict__ mflags,
                                                 unsigned short* __restrict__ out) {
    __shared__ __align__(16) unsigned short Kbuf[2][4096];
    __shared__ __align__(16) unsigned short Vbuf[2][4096];
    __shared__ __align__(16) unsigned short Pbuf[8][16][72];
    const int t = threadIdx.x;
    const int w = t >> 6, l = t & 63;
    const int w4 = w & 3;                    // role within the q-block
    const int g = l >> 4, q16 = l & 15;
    const int x7 = q16 & 7;
    const int bid = blockIdx.x;
    const int swz = (bid & 7) * 128 + (bid >> 3);   // XCD gets contiguous 16-bh chunk
    const int bh = swz >> 3, qpair = swz & 7;
    const int qb = qpair * 2 + (w >> 2);
    const int b = bh >> 4, h = bh & 15;

    const size_t qbase = ((size_t)bh * 1024 + qb * 64 + w4 * 16 + q16) * 64;
    const short8 qf0 = *reinterpret_cast<const short8*>(Qh + qbase + g * 8);
    const short8 qf1 = *reinterpret_cast<const short8*>(Qh + qbase + 32 + g * 8);

    // staging: 512 threads cover a full 64x64 tile in one load (row t>>3, chunk t&7)
    const int r0 = t >> 3;
    const int c0 = ((t & 7) ^ (r0 & 7)) * 8;
    const unsigned short* Kg = Kh + (size_t)bh * 65536 + r0 * 64 + c0;
    const unsigned short* Vg = Vt + (size_t)bh * 65536 + r0 * 1024 + c0;
    const float* mbp = mbias + b * 1024;

#define ATTN_STAGE(bi, kc_)                                                        \
    do {                                                                           \
        gl_lds16(Kg + (kc_) * 4096, &Kbuf[bi][w * 512]);                           \
        gl_lds16(Vg + (kc_) * 64, &Vbuf[bi][w * 512]);                             \
    } while (0)

    ATTN_STAGE(0, 0);

    floatx4 oacc[4] = {};
    floatx4 loacc = {};
    short8 ones;
#pragma unroll
    for (int j = 0; j < 8; ++j) ones[j] = (short)0x3F80;  // bf16 1.0

    int cur = 0;
    for (int kc = 0; kc < 16; ++kc) {
        if (kc < 15) {
            ATTN_STAGE(cur ^ 1, kc + 1);
            asm volatile("s_waitcnt vmcnt(2)" ::: "memory");
        } else {
            asm volatile("s_waitcnt vmcnt(0)" ::: "memory");
        }
        __builtin_amdgcn_s_barrier();
        __builtin_amdgcn_sched_barrier(0);
        const unsigned short* Kb = Kbuf[cur];
        const unsigned short* Vb = Vbuf[cur];

        floatx4 st[4] = {};
        __builtin_amdgcn_s_setprio(1);
#pragma unroll
        for (int t4 = 0; t4 < 4; ++t4) {
            const int row = t4 * 16 + q16;
            const short8 kf0 = *reinterpret_cast<const short8*>(&Kb[row * 64 + (g ^ x7) * 8]);
            const short8 kf1 = *reinterpret_cast<const short8*>(&Kb[row * 64 + ((4 + g) ^ x7) * 8]);
            st[t4] = __builtin_amdgcn_mfma_f32_16x16x32_bf16(kf0, qf0, st[t4], 0, 0, 0);
            st[t4] = __builtin_amdgcn_mfma_f32_16x16x32_bf16(kf1, qf1, st[t4], 0, 0, 0);
        }
        __builtin_amdgcn_s_setprio(0);

        if (mflags[b * 16 + kc]) {
#pragma unroll
            for (int t4 = 0; t4 < 4; ++t4) {
                const float4 mbv = *reinterpret_cast<const float4*>(mbp + kc * 64 + t4 * 16 + g * 4);
#pragma unroll
                for (int r = 0; r < 4; ++r) st[t4][r] += ((const float*)&mbv)[r];
            }
        }
#pragma unroll
        for (int t4 = 0; t4 < 4; ++t4) {
            const float p0 = __builtin_exp2f(st[t4][0]);
            const float p1 = __builtin_exp2f(st[t4][1]);
            const float p2 = __builtin_exp2f(st[t4][2]);
            const float p3 = __builtin_exp2f(st[t4][3]);
            unsigned u0, u1;
            asm("v_cvt_pk_bf16_f32 %0, %1, %2" : "=v"(u0) : "v"(p0), "v"(p1));
            asm("v_cvt_pk_bf16_f32 %0, %1, %2" : "=v"(u1) : "v"(p2), "v"(p3));
            uint2 pr; pr.x = u0; pr.y = u1;
            *reinterpret_cast<uint2*>(&Pbuf[w][q16][t4 * 16 + g * 4]) = pr;
        }

        const short8 pf0 = *reinterpret_cast<const short8*>(&Pbuf[w][q16][g * 8]);
        const short8 pf1 = *reinterpret_cast<const short8*>(&Pbuf[w][q16][32 + g * 8]);
        __builtin_amdgcn_s_setprio(1);
        loacc = __builtin_amdgcn_mfma_f32_16x16x32_bf16(pf0, ones, loacc, 0, 0, 0);
        loacc = __builtin_amdgcn_mfma_f32_16x16x32_bf16(pf1, ones, loacc, 0, 0, 0);
#pragma unroll
        for (int n = 0; n < 4; ++n) {
            const int row = n * 16 + q16;
            const short8 vf0 = *reinterpret_cast<const short8*>(&Vb[row * 64 + (g ^ x7) * 8]);
            const short8 vf1 = *reinterpret_cast<const short8*>(&Vb[row * 64 + ((4 + g) ^ x7) * 8]);
            oacc[n] = __builtin_amdgcn_mfma_f32_16x16x32_bf16(pf0, vf0, oacc[n], 0, 0, 0);
            oacc[n] = __builtin_amdgcn_mfma_f32_16x16x32_bf16(pf1, vf1, oacc[n], 0, 0, 0);
        }
        __builtin_amdgcn_s_setprio(0);
        __builtin_amdgcn_sched_barrier(0);
        __builtin_amdgcn_s_barrier();
        cur ^= 1;
    }
#undef ATTN_STAGE

    const size_t obase = ((size_t)b * S_ + qb * 64 + w4 * 16) * 1024 + h * 64;
#pragma unroll
    for (int r = 0; r < 4; ++r) {
        const float invr = 1.f / loacc[r];
        const size_t orow = obase + (size_t)(g * 4 + r) * 1024;
#pragma unroll
        for (int n = 0; n < 4; ++n)
            out[orow + n * 16 + q16] = f2b(oacc[n][r] * invr);
    }
}

extern "C" void kernel_launch(void* const* d_in, const int* in_sizes, int n_in,
                              void* d_out, int out_size, void* d_ws, size_t ws_size,
                              hipStream_t stream) {
    const float* x   = (const float*)d_in[0];
    const int*  mask = (const int*)d_in[1];
    const float* wq  = (const float*)d_in[2];
    const float* bq  = (const float*)d_in[3];
    const float* wk  = (const float*)d_in[4];
    const float* bk  = (const float*)d_in[5];
    const float* wv  = (const float*)d_in[6];
    const float* bv  = (const float*)d_in[7];
    const float* wo  = (const float*)d_in[8];
    const float* bo  = (const float*)d_in[9];
    const float* w1  = (const float*)d_in[10];
    const float* b1  = (const float*)d_in[11];
    const float* w2  = (const float*)d_in[12];
    const float* b2  = (const float*)d_in[13];
    const float* g1  = (const float*)d_in[14];
    const float* be1 = (const float*)d_in[15];
    const float* g2  = (const float*)d_in[16];
    const float* be2 = (const float*)d_in[17];

    char* ws = (char*)d_ws;
    unsigned short* wqkv_bf = (unsigned short*)(ws);                 // 6 MB
    unsigned short* wo_bf   = (unsigned short*)(ws + 6291456);       // 2 MB
    unsigned short* w1_bf   = (unsigned short*)(ws + 8388608);       // 8 MB
    unsigned short* w2_bf   = (unsigned short*)(ws + 16777216);      // 8 MB
    float*          bqkv    = (float*)(ws + 25165824);               // 12 KB
    float*          mbias   = (float*)(ws + 25178112);               // 32 KB
    int*            mflags  = (int*)(ws + 25210880);                 // 512 B
    unsigned short* h_bf    = (unsigned short*)(ws + 25214976);      // 16 MB
    unsigned short* x1b     = (unsigned short*)(ws + 41992192);      // 16 MB (bf16 x1)
    unsigned short* attn_bf = (unsigned short*)(ws + 75546624);      // 16 MB
    unsigned short* qkvh    = (unsigned short*)(ws + 92323840);      // 48 MB: Qh|Kh|Vt
    unsigned short* ff1_bf  = (unsigned short*)(ws + 92323840);      // 64 MB (overlays qkvh after attn)

    // fused preprocessing + LN1: ONE launch
    prep_kernel<<<20482, 256, 0, stream>>>(wq, wk, wv, wo, w1, w2, bq, bk, bv, mask,
                                           x, g1, be1,
                                           wqkv_bf, wo_bf, w1_bf, w2_bf, bqkv, mbias, mflags, h_bf);

    // QKV projection (128² tiles: 24 x 64), scatter to Qh/Kh/Vt, Q pre-scaled
    gemm_bt<4><<<24 * 64, 256, 0, stream>>>(h_bf, wqkv_bf, bqkv, nullptr, qkvh, NTOK, 3072, 1024, 24);
    // flash attention (8 waves / 2 q-blocks sharing K/V)
    attn_mfma<<<1024, 512, 0, stream>>>(qkvh, qkvh + 8388608, qkvh + 16777216, mbias, mflags, attn_bf);
    // O-projection + residual -> bf16 x1b (128² tiles: 8 x 64)
    gemm_bt<2><<<8 * 64, 256, 0, stream>>>(attn_bf, wo_bf, bo, x, x1b, NTOK, 1024, 1024, 8);
    // LN2 (bf16 input)
    ln_bf16<<<NTOK, 256, 0, stream>>>(x1b, g2, be2, h_bf);
    // FFN1 + ReLU (phase-pipelined 256² tiles: 32 x 16 = 512 blocks)
    gemm256p<<<512, 512, 0, stream>>>(h_bf, w1_bf, b1, ff1_bf, NTOK, 4096, 1024, 16);
    // FFN2 + bf16 residual -> fp32 out (128² tiles: 8 x 64)
    gemm_bt<5><<<8 * 64, 256, 0, stream>>>(ff1_bf, w2_bf, b2, x1b, (float*)d_out, NTOK, 1024, 4096, 8);
}